// Round 12
// baseline (398.236 us; speedup 1.0000x reference)
//
#include <hip/hip_runtime.h>

// RoiCut: out[i, c, y, x] = fm[assoc[i], c, y0_i + y, x0_i + x]
// fm: [8, 256, 200, 200] fp32, boxes_yx: [512, 2] int32 (y0, x0), assoc: [512] int32
// out: [512, 256, 32, 32] fp32
//
// R11: MEASUREMENT ROUND. R8 (best, 168.9 us) byte-identical, PLUS an
// appended out->out identity-copy control kernel (512 MB read + 512 MB write,
// plain loads + nt stores — same instruction pattern as the main kernel).
// Purpose: empirically measure the achievable mixed read+write HBM rate on
// this device/buffers. control_dur = total_dur - 168.9; rate = 1.074GB/control.
// The control is value-preserving (identity), deterministic, stream-ordered
// after the main kernel -> validation- and graph-capture-safe.

typedef float v4f __attribute__((ext_vector_type(4)));

constexpr int C_     = 256;
constexpr int H_     = 200;
constexpr int W_     = 200;
constexpr int BOX_   = 32;
constexpr int N_     = 512;
constexpr int B_     = 8;
constexpr int PLANE  = H_ * W_;       // 40000 floats
constexpr int HROWS  = 100;           // rows per half
constexpr int HLDS   = HROWS * W_;    // 20000 floats = 80,000 B
constexpr int HLDS4  = HLDS / 4;      // 5000 float4

__global__ __launch_bounds__(512) void group_boxes_kernel(
    const int* __restrict__ boxes,
    const int* __restrict__ assoc,
    unsigned int* __restrict__ keys,
    int* __restrict__ starts)
{
    __shared__ int cnt[B_];
    __shared__ int base[B_ + 1];
    int t = threadIdx.x;   // 512 threads, one per box

    if (t < B_) cnt[t] = 0;
    __syncthreads();

    int y0 = boxes[2 * t];
    int x0 = boxes[2 * t + 1];
    y0 = min(max(y0, 0), H_ - BOX_);
    x0 = min(max(x0, 0), W_ - BOX_);
    int a = assoc[t];
    int pos = atomicAdd(&cnt[a], 1);   // order nondeterminism benign (disjoint outputs)
    __syncthreads();

    if (t == 0) {
        int s = 0;
        for (int i = 0; i < B_; ++i) { base[i] = s; s += cnt[i]; }
        base[B_] = s;
    }
    __syncthreads();

    // key: [y0:8 | x0:8 | idx:9]
    keys[base[a] + pos] = ((unsigned int)y0 << 17) | ((unsigned int)x0 << 9) | (unsigned int)t;
    if (t <= B_) starts[t] = base[t];
}

__global__ __launch_bounds__(1024, 8) void roicut_kernel(
    const float* __restrict__ fm,
    const unsigned int* __restrict__ keys,
    const int* __restrict__ starts,
    float* __restrict__ out)
{
    extern __shared__ float lds[];   // 80,000 B = half plane (100 rows x 200)

    int bid = blockIdx.x;
    int h = bid & 1;                 // half: rows [100h, 100h+100)
    int c = (bid >> 1) & 255;        // channel
    int a = bid >> 9;                // sample
    int t = threadIdx.x;             // 1024 threads

    // ---- stage half plane into LDS (canonical conflict-free b128 pattern) ----
    const v4f* src = (const v4f*)(fm + (size_t)(a * C_ + c) * PLANE) + h * HLDS4;
    v4f* l4 = (v4f*)lds;
    v4f r0 = src[t];
    v4f r1 = src[t + 1024];
    v4f r2 = src[t + 2048];
    v4f r3 = src[t + 3072];
    bool tail = t < (HLDS4 - 4096);   // t < 904
    v4f r4;
    if (tail) r4 = src[t + 4096];
    l4[t]        = r0;
    l4[t + 1024] = r1;
    l4[t + 2048] = r2;
    l4[t + 3072] = r3;
    if (tail) l4[t + 4096] = r4;
    __syncthreads();

    // ---- box loop: 4 boxes in flight (sub = 4 waves each) ----
    int b0 = starts[a], b1 = starts[a + 1];
    int sub = t >> 8;             // 0..3
    int q   = t & 255;            // pixel-quad within box tile
    int y   = q >> 3;             // 0..31
    int xg  = (q & 7) << 2;       // 0,4,...,28
    int rot = y & 3;              // per-row XOR rotation for bank spreading
    int hbase = h * HROWS;        // first plane row owned by this half

    for (int b = b0; b < b1; b += 4) {
        int bb = b + sub;
        if (bb < b1) {
            unsigned int v = keys[bb];
            int y0 = (v >> 17) & 255;
            int x0 = (v >> 9) & 255;
            int i  = (int)(v & 511u);
            int ly = y0 + y - hbase;          // row within this half
            if (ly >= 0 && ly < HROWS) {      // predicated rows (straddling boxes)
                const float* p = lds + ly * W_ + (x0 + xg);
                // XOR-rotated reads: instruction m touches element (m ^ rot);
                // per instruction, lanes cover 32 banks at 2-way -> conflict-free.
                v4f vv;
                vv[0] = p[0 ^ rot];
                vv[1] = p[1 ^ rot];
                vv[2] = p[2 ^ rot];
                vv[3] = p[3 ^ rot];
                // un-rotate: out[d] = vv[d ^ rot], via two conditional swaps
                v4f s1 = { vv[1], vv[0], vv[3], vv[2] };   // xor-by-1 shuffle
                vv = (rot & 1) ? s1 : vv;
                v4f s2 = { vv[2], vv[3], vv[0], vv[1] };   // xor-by-2 shuffle
                vv = (rot & 2) ? s2 : vv;
                v4f* dst = (v4f*)(out + (((size_t)i << 18) + ((size_t)c << 10) + (size_t)(q << 2)));
                __builtin_nontemporal_store(vv, dst);
            }
        }
    }
}

// ---- identity-copy control: measures mixed read+write HBM rate in-band ----
// src and dst are the SAME buffer at runtime (out), passed as separate
// non-restrict pointers so the compiler cannot fold the load/store pair.
__global__ __launch_bounds__(256) void copy_control_kernel(
    const v4f* src, v4f* dst, long n4)
{
    long stride = (long)gridDim.x * blockDim.x;
    long idx = (long)blockIdx.x * blockDim.x + threadIdx.x;
    for (; idx < n4; idx += 4 * stride) {
        long i0 = idx;
        long i1 = idx + stride;
        long i2 = idx + 2 * stride;
        long i3 = idx + 3 * stride;
        v4f a = src[i0];
        v4f b = (i1 < n4) ? src[i1] : a;
        v4f c = (i2 < n4) ? src[i2] : a;
        v4f d = (i3 < n4) ? src[i3] : a;
        __builtin_nontemporal_store(a, dst + i0);
        if (i1 < n4) __builtin_nontemporal_store(b, dst + i1);
        if (i2 < n4) __builtin_nontemporal_store(c, dst + i2);
        if (i3 < n4) __builtin_nontemporal_store(d, dst + i3);
    }
}

extern "C" void kernel_launch(void* const* d_in, const int* in_sizes, int n_in,
                              void* d_out, int out_size, void* d_ws, size_t ws_size,
                              hipStream_t stream) {
    const float* fm    = (const float*)d_in[0];
    const int*   boxes = (const int*)d_in[1];
    const int*   assoc = (const int*)d_in[2];
    float*       out   = (float*)d_out;

    unsigned int* keys   = (unsigned int*)d_ws;        // 512 u32
    int*          starts = (int*)d_ws + N_;            // 9 ints

    // allow 80,000 B dynamic LDS (host-side attribute; idempotent, no stream op)
    (void)hipFuncSetAttribute((const void*)roicut_kernel,
                              hipFuncAttributeMaxDynamicSharedMemorySize,
                              HLDS * (int)sizeof(float));

    group_boxes_kernel<<<1, N_, 0, stream>>>(boxes, assoc, keys, starts);

    int grid = B_ * C_ * 2;   // 4096 blocks: one per (sample, channel, half)
    roicut_kernel<<<grid, 1024, HLDS * sizeof(float), stream>>>(fm, keys, starts, out);

    // measurement control: identity copy over the output buffer (1.074 GB bus)
    long n4 = (long)out_size / 4;
    copy_control_kernel<<<2048, 256, 0, stream>>>((const v4f*)out, (v4f*)out, n4);
}

// Round 13
// 168.215 us; speedup vs baseline: 2.3674x; 2.3674x over previous
//
#include <hip/hip_runtime.h>

// RoiCut: out[i, c, y, x] = fm[assoc[i], c, y0_i + y, x0_i + x]
// fm: [8, 256, 200, 200] fp32, boxes_yx: [512, 2] int32 (y0, x0), assoc: [512] int32
// out: [512, 256, 32, 32] fp32
//
// FINAL (R8 structure, measured-roofline): 168.9 us.
//  - Roofline evidence (R11/R12 in-band control): identity copy with identical
//    nt-dwordx4 store pattern sustains 4.68 TB/s; this kernel moves
//    839 MB (327 read + 512 write) at 5.03 TB/s effective — above the
//    same-pattern copy ceiling. Overlap/scheduling variants (prefetch,
//    phase-mixing, cache-through, counted-vmcnt) all regressed.
//  - Structure: block = (sample, channel, half-plane); 100 rows staged to
//    80,000 B LDS with exact-once perfectly-coalesced b128 reads (2 blocks/CU).
//  - Box loop: 4 boxes in flight; rot-XOR LDS reads (elem m ^ (row&3)) spread
//    each ds_read across 32 banks at 2-way -> conflict-free (A/B: +3.6 us).
//  - Non-temporal dwordx4 stores (A/B: +8 us vs plain).
//  - Counting-scatter grouping kernel (~2 us); within-sample box order is
//    irrelevant (disjoint output tiles) so LDS-atomic order nondeterminism
//    does not affect output bytes.

typedef float v4f __attribute__((ext_vector_type(4)));

constexpr int C_     = 256;
constexpr int H_     = 200;
constexpr int W_     = 200;
constexpr int BOX_   = 32;
constexpr int N_     = 512;
constexpr int B_     = 8;
constexpr int PLANE  = H_ * W_;       // 40000 floats
constexpr int HROWS  = 100;           // rows per half
constexpr int HLDS   = HROWS * W_;    // 20000 floats = 80,000 B
constexpr int HLDS4  = HLDS / 4;      // 5000 float4

__global__ __launch_bounds__(512) void group_boxes_kernel(
    const int* __restrict__ boxes,
    const int* __restrict__ assoc,
    unsigned int* __restrict__ keys,
    int* __restrict__ starts)
{
    __shared__ int cnt[B_];
    __shared__ int base[B_ + 1];
    int t = threadIdx.x;   // 512 threads, one per box

    if (t < B_) cnt[t] = 0;
    __syncthreads();

    int y0 = boxes[2 * t];
    int x0 = boxes[2 * t + 1];
    y0 = min(max(y0, 0), H_ - BOX_);
    x0 = min(max(x0, 0), W_ - BOX_);
    int a = assoc[t];
    int pos = atomicAdd(&cnt[a], 1);   // order nondeterminism benign (disjoint outputs)
    __syncthreads();

    if (t == 0) {
        int s = 0;
        for (int i = 0; i < B_; ++i) { base[i] = s; s += cnt[i]; }
        base[B_] = s;
    }
    __syncthreads();

    // key: [y0:8 | x0:8 | idx:9]
    keys[base[a] + pos] = ((unsigned int)y0 << 17) | ((unsigned int)x0 << 9) | (unsigned int)t;
    if (t <= B_) starts[t] = base[t];
}

__global__ __launch_bounds__(1024, 8) void roicut_kernel(
    const float* __restrict__ fm,
    const unsigned int* __restrict__ keys,
    const int* __restrict__ starts,
    float* __restrict__ out)
{
    extern __shared__ float lds[];   // 80,000 B = half plane (100 rows x 200)

    int bid = blockIdx.x;
    int h = bid & 1;                 // half: rows [100h, 100h+100)
    int c = (bid >> 1) & 255;        // channel
    int a = bid >> 9;                // sample
    int t = threadIdx.x;             // 1024 threads

    // ---- stage half plane into LDS (canonical conflict-free b128 pattern) ----
    const v4f* src = (const v4f*)(fm + (size_t)(a * C_ + c) * PLANE) + h * HLDS4;
    v4f* l4 = (v4f*)lds;
    v4f r0 = src[t];
    v4f r1 = src[t + 1024];
    v4f r2 = src[t + 2048];
    v4f r3 = src[t + 3072];
    bool tail = t < (HLDS4 - 4096);   // t < 904
    v4f r4;
    if (tail) r4 = src[t + 4096];
    l4[t]        = r0;
    l4[t + 1024] = r1;
    l4[t + 2048] = r2;
    l4[t + 3072] = r3;
    if (tail) l4[t + 4096] = r4;
    __syncthreads();

    // ---- box loop: 4 boxes in flight (sub = 4 waves each) ----
    int b0 = starts[a], b1 = starts[a + 1];
    int sub = t >> 8;             // 0..3
    int q   = t & 255;            // pixel-quad within box tile
    int y   = q >> 3;             // 0..31
    int xg  = (q & 7) << 2;       // 0,4,...,28
    int rot = y & 3;              // per-row XOR rotation for bank spreading
    int hbase = h * HROWS;        // first plane row owned by this half

    for (int b = b0; b < b1; b += 4) {
        int bb = b + sub;
        if (bb < b1) {
            unsigned int v = keys[bb];
            int y0 = (v >> 17) & 255;
            int x0 = (v >> 9) & 255;
            int i  = (int)(v & 511u);
            int ly = y0 + y - hbase;          // row within this half
            if (ly >= 0 && ly < HROWS) {      // predicated rows (straddling boxes)
                const float* p = lds + ly * W_ + (x0 + xg);
                // XOR-rotated reads: instruction m touches element (m ^ rot);
                // per instruction, lanes cover 32 banks at 2-way -> conflict-free.
                v4f vv;
                vv[0] = p[0 ^ rot];
                vv[1] = p[1 ^ rot];
                vv[2] = p[2 ^ rot];
                vv[3] = p[3 ^ rot];
                // un-rotate: out[d] = vv[d ^ rot], via two conditional swaps
                v4f s1 = { vv[1], vv[0], vv[3], vv[2] };   // xor-by-1 shuffle
                vv = (rot & 1) ? s1 : vv;
                v4f s2 = { vv[2], vv[3], vv[0], vv[1] };   // xor-by-2 shuffle
                vv = (rot & 2) ? s2 : vv;
                v4f* dst = (v4f*)(out + (((size_t)i << 18) + ((size_t)c << 10) + (size_t)(q << 2)));
                __builtin_nontemporal_store(vv, dst);
            }
        }
    }
}

extern "C" void kernel_launch(void* const* d_in, const int* in_sizes, int n_in,
                              void* d_out, int out_size, void* d_ws, size_t ws_size,
                              hipStream_t stream) {
    const float* fm    = (const float*)d_in[0];
    const int*   boxes = (const int*)d_in[1];
    const int*   assoc = (const int*)d_in[2];
    float*       out   = (float*)d_out;

    unsigned int* keys   = (unsigned int*)d_ws;        // 512 u32
    int*          starts = (int*)d_ws + N_;            // 9 ints

    // allow 80,000 B dynamic LDS (host-side attribute; idempotent, no stream op)
    (void)hipFuncSetAttribute((const void*)roicut_kernel,
                              hipFuncAttributeMaxDynamicSharedMemorySize,
                              HLDS * (int)sizeof(float));

    group_boxes_kernel<<<1, N_, 0, stream>>>(boxes, assoc, keys, starts);

    int grid = B_ * C_ * 2;   // 4096 blocks: one per (sample, channel, half)
    roicut_kernel<<<grid, 1024, HLDS * sizeof(float), stream>>>(fm, keys, starts, out);
}